// Round 9
// baseline (222.476 us; speedup 1.0000x reference)
//
#include <hip/hip_runtime.h>
#include <math.h>

#define HH 960
#define WW 1280
#define NPIX (HH*WW)
#define BPR (WW/256)              // 5 col-segments per image row
#define NBLK_ROW (NPIX/256)       // 4800 row-mapped tiles (pre phase)
#define NBLK_MAIN (NPIX/(256*4))  // 1200: 4-row x 256-col tiles (main phase, R11 proven)
#define TROWS 6                   // 4 output rows + 2 halo
#define TW 258                    // x0 tile width (256 + 2 halo)

// workspace layout (bytes)
#define WS_S_OFF   0              // 3 slots x 32 floats (JtWJ/JtR sums per iteration) = 384 B
#define WS_NX_OFF  512            // NPIX * 16 B = 19660800 B -> total ~19.7 MB

__device__ __forceinline__ int clampi(int v, int lo, int hi){ return v<lo?lo:(v>hi?hi:v); }

// pack two f32 -> one dword of 2 x f16 (lo = a, hi = b)
__device__ __forceinline__ float pack2h(float a, float b){
  _Float16 ha = (_Float16)a, hb = (_Float16)b;
  unsigned int u = ((unsigned int)__builtin_bit_cast(unsigned short, hb) << 16)
                 |  (unsigned int)__builtin_bit_cast(unsigned short, ha);
  return __builtin_bit_cast(float, u);
}
// unpack one dword of 2 x f16 -> (lo, hi) as f32
__device__ __forceinline__ float2 unpack2h(float p){
  unsigned int u = __builtin_bit_cast(unsigned int, p);
  _Float16 ha = __builtin_bit_cast(_Float16, (unsigned short)(u & 0xffffu));
  _Float16 hb = __builtin_bit_cast(_Float16, (unsigned short)(u >> 16));
  return make_float2((float)ha, (float)hb);
}

// ---------------- wave-cooperative damped 6x6 solve chain (lanes 0-5 own rows) ----------------
// R15: runs in wave 0 of every k_main block; chains `nsteps` solves from pose_in using the
// atomically-accumulated S slots. Float throughout (R10 validated float solve, absmax 0.0).
// All per-thread arrays statically indexed via #pragma unroll (rule #20); pose P lives in LDS
// (sp[12]) between steps to keep VGPR <= 64 (R12 lesson: crossing 64 halves occupancy).
__device__ __forceinline__ void wave_chain_solve(const float* __restrict__ S, int nsteps,
                                                 const float* __restrict__ pose_in,
                                                 float* sp, int lane){
  if (lane < 12) sp[lane] = pose_in[lane];
  int r = lane < 6 ? lane : 5;
  for (int step = 0; step < nsteps; ++step){
    const float* s = S + step*32;
    // lane r builds its row of the damped system: a[0..5] = H[r][*], a[6] = b[r]
    float a[7];
    #pragma unroll
    for (int j = 0; j < 6; j++){
      int i = r < j ? r : j, J = r < j ? j : r;
      a[j] = s[6*i - (i*(i-1))/2 + (J - i)];
    }
    a[6] = s[21 + r];
    float tr = s[0]+s[6]+s[11]+s[15]+s[18]+s[20];
    float damp = tr*0.001f;
    #pragma unroll
    for (int j = 0; j < 6; j++) a[j] += (r == j) ? damp : 0.f;
    // pivot-free Gauss-Jordan (H is SPD + damped), pivot row broadcast via shfl
    float mydiag = 1.f;
    #pragma unroll
    for (int c = 0; c < 6; c++){
      float pv[7];
      #pragma unroll
      for (int j = 0; j < 7; j++) pv[j] = __shfl(a[j], c);
      float f = a[c] * (1.0f/pv[c]);
      bool self = (r == c);
      if (self) mydiag = a[c];
      float fr = self ? 0.f : f;
      #pragma unroll
      for (int j = 0; j < 7; j++) a[j] -= fr*pv[j];
    }
    float xir = a[6] / mydiag;
    float xi[6];
    #pragma unroll
    for (int j = 0; j < 6; j++) xi[j] = __shfl(xir, j);
    // dR = exp_so3(-w);  W^2 = w w^T - |w|^2 I  =>  dR = (1-sb*th2) I + sb w w^T + sa W
    float wx = -xi[0], wy = -xi[1], wz = -xi[2];
    float th2 = wx*wx + wy*wy + wz*wz; if (th2 < 1e-30f) th2 = 1e-30f;
    float th = sqrtf(th2);
    float dR[9];
    if (th <= 1e-10f){
      dR[0]=1.f;dR[1]=0.f;dR[2]=0.f; dR[3]=0.f;dR[4]=1.f;dR[5]=0.f; dR[6]=0.f;dR[7]=0.f;dR[8]=1.f;
    } else {
      float sa = sinf(th)/th, sb = (1.f - cosf(th))/th2;
      float cI = 1.f - sb*th2;
      dR[0]=cI + sb*wx*wx;    dR[1]=sb*wx*wy - sa*wz; dR[2]=sb*wx*wz + sa*wy;
      dR[3]=sb*wy*wx + sa*wz; dR[4]=cI + sb*wy*wy;    dR[5]=sb*wy*wz - sa*wx;
      dR[6]=sb*wz*wx - sa*wy; dR[7]=sb*wz*wy + sa*wx; dR[8]=cI + sb*wz*wz;
    }
    float dt0 = -(dR[0]*xi[3] + dR[1]*xi[4] + dR[2]*xi[5]);
    float dt1 = -(dR[3]*xi[3] + dR[4]*xi[4] + dR[5]*xi[5]);
    float dt2 = -(dR[6]*xi[3] + dR[7]*xi[4] + dR[8]*xi[5]);
    // compose (all lanes redundantly, wave-uniform): Pn = dR * P
    float Ro[12];
    #pragma unroll
    for (int j = 0; j < 12; j++) Ro[j] = sp[j];
    float Pn[12];
    #pragma unroll
    for (int i = 0; i < 3; i++){
      #pragma unroll
      for (int j = 0; j < 3; j++)
        Pn[i*4+j] = dR[i*3+0]*Ro[0*4+j] + dR[i*3+1]*Ro[1*4+j] + dR[i*3+2]*Ro[2*4+j];
      Pn[i*4+3] = dR[i*3+0]*Ro[3] + dR[i*3+1]*Ro[7] + dR[i*3+2]*Ro[11]
                + (i==0 ? dt0 : (i==1 ? dt1 : dt2));
    }
    if (lane == 0){
      sp[0]=Pn[0]; sp[1]=Pn[1]; sp[2]=Pn[2];  sp[3]=Pn[3];
      sp[4]=Pn[4]; sp[5]=Pn[5]; sp[6]=Pn[6];  sp[7]=Pn[7];
      sp[8]=Pn[8]; sp[9]=Pn[9]; sp[10]=Pn[10]; sp[11]=Pn[11];
    }
  }
}

// ---------------- pre: zero S slots + normals + packed [d f32 | n f16x3 | rgb f16x3] ----------------
// R10 (kept): global depth-min/max invalidation dropped — verified bit-exact.
// R14 (kept): nx1 packed 16 B/pixel. R15: also zeroes the 3 atomic sum slots.
__global__ __launch_bounds__(256) void k_pre(const float* __restrict__ depth1,
                                             const float* __restrict__ x1,
                                             const float* __restrict__ Kd,
                                             float* __restrict__ S,
                                             float* __restrict__ nx1){
  int t = threadIdx.x;
  if (blockIdx.x == 0 && t < 96) S[t] = 0.f;
  int bid = blockIdx.x;
  int py = bid / BPR;
  int px = (bid % BPR)*256 + t;
  float fx = Kd[0], fy = Kd[4], cx = Kd[2], cy = Kd[5];
  float invfx = 1.f/fx, invfy = 1.f/fy;
  float vx[3][3], vy[3][3], vz[3][3];
  #pragma unroll
  for (int dr = 0; dr < 3; dr++){
    int r = clampi(py + dr - 1, 0, HH-1);
    #pragma unroll
    for (int dc = 0; dc < 3; dc++){
      int c = clampi(px + dc - 1, 0, WW-1);
      float d = depth1[r*WW + c];
      vx[dr][dc] = ((float)c - cx)*invfx*d;
      vy[dr][dc] = ((float)r - cy)*invfy*d;
      vz[dr][dc] = d;
    }
  }
  float ax_ = (vx[0][2]-vx[0][0]) + 2.f*(vx[1][2]-vx[1][0]) + (vx[2][2]-vx[2][0]);
  float ay_ = (vy[0][2]-vy[0][0]) + 2.f*(vy[1][2]-vy[1][0]) + (vy[2][2]-vy[2][0]);
  float az_ = (vz[0][2]-vz[0][0]) + 2.f*(vz[1][2]-vz[1][0]) + (vz[2][2]-vz[2][0]);
  float bx_ = (vx[2][0]-vx[0][0]) + 2.f*(vx[2][1]-vx[0][1]) + (vx[2][2]-vx[0][2]);
  float by_ = (vy[2][0]-vy[0][0]) + 2.f*(vy[2][1]-vy[0][1]) + (vy[2][2]-vy[0][2]);
  float bz_ = (vz[2][0]-vz[0][0]) + 2.f*(vz[2][1]-vz[0][1]) + (vz[2][2]-vz[0][2]);
  float nx = ay_*bz_ - az_*by_;
  float ny = az_*bx_ - ax_*bz_;
  float nz = ax_*by_ - ay_*bx_;
  float nrm = sqrtf(nx*nx + ny*ny + nz*nz) + 1e-8f;
  float rn  = __builtin_amdgcn_rcpf(nrm);
  nx *= rn; ny *= rn; nz *= rn;
  float dcen = vz[1][1];
  int idx = py*WW + px;
  const float* q = &x1[idx*3];
  float4 a;
  a.x = dcen;
  a.y = pack2h(nx, ny);
  a.z = pack2h(nz, q[0]);
  a.w = pack2h(q[1], q[2]);
  ((float4*)nx1)[idx] = a;
}

// ---------------- fused per-pixel ICP + RGB accumulation + atomic sums + in-kernel pose chain ----
// R11 structure (4-row/256-thr/1200 blocks) + R14 packed gathers.
// R15: pose(it) recomputed per block by wave 0 (chain of `it` solves from pose10); block
// partials atomicAdd'ed into S[it] — removes the 3 k_solve dispatches.
__global__ __launch_bounds__(256) void k_main(const float* __restrict__ depth0,
                                              const float* __restrict__ x0,
                                              const float* __restrict__ nx1,
                                              const float* __restrict__ Kd,
                                              const float* __restrict__ pose10,
                                              float* __restrict__ S,
                                              int it){
  int t = threadIdx.x;
  // XCD-aware swizzle: contiguous 150-tile (120-row) band per XCD (R6: FETCH 92->29 MB)
  int bid = (blockIdx.x & 7)*(NBLK_MAIN/8) + (blockIdx.x >> 3);
  int pr = bid / BPR;
  int cs = bid % BPR;
  int py0 = pr*4;
  int colbase = cs*256 - 1;
  int px = cs*256 + t;

  __shared__ float tile[TROWS*TW*3];    // 18576 B
  __shared__ float sp[12];
  for (int s = t; s < TROWS*TW; s += 256){
    int r = s / TW, c = s - r*TW;
    int gr = clampi(py0 - 1 + r, 0, HH-1);
    int gc = clampi(colbase + c, 0, WW-1);
    const float* q = &x0[(gr*WW + gc)*3];
    tile[s*3+0] = q[0]; tile[s*3+1] = q[1]; tile[s*3+2] = q[2];
  }

  // prefetch depth0 values before the barrier (independent of LDS)
  int idx0 = py0*WW + px;
  float d0v[4];
  #pragma unroll
  for (int kp = 0; kp < 4; kp++) d0v[kp] = depth0[idx0 + kp*WW];

  // wave 0: recompute pose chain (it solves) into sp[12]
  if (t < 64) wave_chain_solve(S, it, pose10, sp, t);
  __syncthreads();

  float fx = Kd[0], fy = Kd[4], cx = Kd[2], cy = Kd[5];
  float inv_fx = 1.f/fx, inv_fy = 1.f/fy;
  float R00=sp[0], R01=sp[1], R02=sp[2],  tx=sp[3];
  float R10=sp[4], R11=sp[5], R12=sp[6],  ty=sp[7];
  float R20=sp[8], R21=sp[9], R22=sp[10], tz=sp[11];

  float acc[27];
  #pragma unroll
  for (int k = 0; k < 27; k++) acc[k] = 0.f;

  const float4* nx4 = (const float4*)nx1;

  #pragma unroll
  for (int kp = 0; kp < 4; kp++){
    int py = py0 + kp;

    float d0 = d0v[kp];
    bool m0 = d0 > 0.f;
    float v0x = ((float)px - cx)*inv_fx*d0;
    float v0y = ((float)py - cy)*inv_fy*d0;
    float v0z = d0;
    float X = R00*v0x + R01*v0y + R02*v0z + tx;
    float Y = R10*v0x + R11*v0y + R12*v0z + ty;
    float Z = R20*v0x + R21*v0y + R22*v0z + tz;
    // 1/Z via rcp + one Newton step (drives u,v indices)
    float invZ = __builtin_amdgcn_rcpf(Z);
    invZ = invZ*(2.0f - Z*invZ);
    float u = X*invZ*fx + cx;
    float v = Y*invZ*fy + cy;
    bool inview = (u > 0.f) && (u < (float)(WW-1)) && (v > 0.f) && (v < (float)(HH-1)) && (Z > 0.f);

    float uc = fminf(fmaxf(u, 0.f), (float)(WW-1));
    float vc = fminf(fmaxf(v, 0.f), (float)(HH-1));
    float u0f = floorf(uc), v0f = floorf(vc);
    float wu = uc - u0f, wv = vc - v0f;
    int u0i = clampi((int)u0f, 0, WW-1);
    int v0i = clampi((int)v0f, 0, HH-1);
    int u1i = min(u0i + 1, WW-1);
    int v1i = min(v0i + 1, HH-1);
    int i00 = v0i*WW + u0i, i01 = v0i*WW + u1i, i10 = v1i*WW + u0i, i11 = v1i*WW + u1i;
    float w00 = (1.f-wu)*(1.f-wv), w01 = wu*(1.f-wv), w10 = (1.f-wu)*wv, w11 = wu*wv;

    float4 p00 = nx4[i00], p01 = nx4[i01], p10 = nx4[i10], p11v = nx4[i11];

    // unpack: .x = d (f32), .y = nx|ny, .z = nz|r, .w = g|b
    float2 nab00 = unpack2h(p00.y), nzr00 = unpack2h(p00.z);
    float2 nab01 = unpack2h(p01.y), nzr01 = unpack2h(p01.z);
    float2 nab10 = unpack2h(p10.y), nzr10 = unpack2h(p10.z);
    float2 nab11 = unpack2h(p11v.y), nzr11 = unpack2h(p11v.z);

    // factored vertex interpolation (d exact f32)
    float t0 = w00*p00.x, t1 = w01*p01.x, t2 = w10*p10.x, t3 = w11*p11v.x;
    float u0c = ((float)u0i - cx)*inv_fx, u1c = ((float)u1i - cx)*inv_fx;
    float v0c = ((float)v0i - cy)*inv_fy, v1c = ((float)v1i - cy)*inv_fy;
    float s2 = (t0+t1)+(t2+t3);
    float s0 = u0c*(t0+t2) + u1c*(t1+t3);
    float s1 = v0c*(t0+t1) + v1c*(t2+t3);
    float nx = nab00.x*w00 + nab01.x*w01 + nab10.x*w10 + nab11.x*w11;
    float ny = nab00.y*w00 + nab01.y*w01 + nab10.y*w10 + nab11.y*w11;
    float nz = nzr00.x*w00 + nzr01.x*w01 + nzr10.x*w10 + nzr11.x*w11;

    float dfx = X - s0, dfy = Y - s1, dfz = Z - s2;
    bool valid = inview && m0 && (s2 > 0.f) && (dfx*dfx + dfy*dfy + dfz*dfz < 0.01f);
    float res = 0.f;
    float J[6] = {0.f,0.f,0.f,0.f,0.f,0.f};
    if (valid){
      res = nx*dfx + ny*dfy + nz*dfz;
      J[0] = Y*nz - Z*ny;
      J[1] = Z*nx - X*nz;
      J[2] = X*ny - Y*nx;
      J[3] = nx; J[4] = ny; J[5] = nz;
    }
    float axv = fabsf(res);
    float rho = (axv <= 0.02f) ? axv*axv : (0.04f*axv - 0.0004f);
    float xs  = (axv < 1e-8f) ? 1.f : axv;
    float hw  = sqrtf(rho + 1e-16f) * __builtin_amdgcn_rcpf(xs);
    float wr  = hw*res;
    float wJ[6];
    #pragma unroll
    for (int i = 0; i < 6; i++) wJ[i] = hw*J[i];
    {
      int k = 0;
      #pragma unroll
      for (int i = 0; i < 6; i++)
        #pragma unroll
        for (int j = i; j < 6; j++)
          acc[k++] += wJ[i]*wJ[j];
      #pragma unroll
      for (int i = 0; i < 6; i++) acc[21+i] += wJ[i]*wr;
    }

    if (inview && m0){
      float2 gb00 = unpack2h(p00.w), gb01 = unpack2h(p01.w);
      float2 gb10 = unpack2h(p10.w), gb11 = unpack2h(p11v.w);
      float xw[3];
      xw[0] = nzr00.y*w00 + nzr01.y*w01 + nzr10.y*w10 + nzr11.y*w11;
      xw[1] = gb00.x*w00 + gb01.x*w01 + gb10.x*w10 + gb11.x*w11;
      xw[2] = gb00.y*w00 + gb01.y*w01 + gb10.y*w10 + gb11.y*w11;

      // gradient Gram scalars; direct LDS reads (R6), rsq instead of sqrt+2div (R7)
      float ga = 0.f, gb = 0.f, gc2 = 0.f, rx = 0.f, ry = 0.f;
      #pragma unroll
      for (int ch = 0; ch < 3; ch++){
        float p00l = tile[((kp+0)*TW + (t+0))*3 + ch];
        float p01l = tile[((kp+0)*TW + (t+1))*3 + ch];
        float p02l = tile[((kp+0)*TW + (t+2))*3 + ch];
        float p10l = tile[((kp+1)*TW + (t+0))*3 + ch];
        float p11l = tile[((kp+1)*TW + (t+1))*3 + ch];
        float p12l = tile[((kp+1)*TW + (t+2))*3 + ch];
        float p20l = tile[((kp+2)*TW + (t+0))*3 + ch];
        float p21l = tile[((kp+2)*TW + (t+1))*3 + ch];
        float p22l = tile[((kp+2)*TW + (t+2))*3 + ch];
        float dx = (p02l-p00l) + 2.f*(p12l-p10l) + (p22l-p20l);
        float dy = (p20l-p00l) + 2.f*(p21l-p01l) + (p22l-p02l);
        float rinv = __builtin_amdgcn_rsqf(dx*dx + dy*dy + 1e-8f);
        float gx = dx*rinv, gy = dy*rinv;
        float rr = xw[ch] - p11l;
        ga  += gx*gx; gb += gx*gy; gc2 += gy*gy;
        rx  += gx*rr; ry += gy*rr;
      }
      ga *= 1e-6f; gb *= 1e-6f; gc2 *= 1e-6f; rx *= 1e-6f; ry *= 1e-6f;

      float invD = __builtin_amdgcn_rcpf(d0), invD2 = invD*invD;
      float xy = v0x*v0y;
      float Jx[6] = { fx*(-invD2*xy), fx*(1.f + v0x*v0x*invD2), fx*(-v0y*invD), fx*invD, 0.f, fx*(-invD2*v0x) };
      float Jy[6] = { fy*(-1.f - invD2*v0y*v0y), fy*(xy*invD2), fy*(v0x*invD), 0.f, fy*invD, fy*(-invD2*v0y) };
      float P[6], Q[6];
      #pragma unroll
      for (int i = 0; i < 6; i++){ P[i] = ga*Jx[i] + gb*Jy[i]; Q[i] = gb*Jx[i] + gc2*Jy[i]; }
      int k = 0;
      #pragma unroll
      for (int i = 0; i < 6; i++)
        #pragma unroll
        for (int j = i; j < 6; j++)
          acc[k++] += Jx[j]*P[i] + Jy[j]*Q[i];
      #pragma unroll
      for (int i = 0; i < 6; i++) acc[21+i] += Jx[i]*rx + Jy[i]*ry;
    }
  }

  // block reduction: wave shfl -> LDS -> 27 atomic adds into S[it]
  __shared__ float lds[108];
  int lane = t & 63;
  int wid  = t >> 6;
  #pragma unroll
  for (int k = 0; k < 27; k++){
    float vv = acc[k];
    vv += __shfl_down(vv, 32); vv += __shfl_down(vv, 16); vv += __shfl_down(vv, 8);
    vv += __shfl_down(vv, 4);  vv += __shfl_down(vv, 2);  vv += __shfl_down(vv, 1);
    if (lane == 0) lds[wid*27 + k] = vv;
  }
  __syncthreads();
  if (t < 27)
    atomicAdd(&S[it*32 + t], lds[t] + lds[27+t] + lds[54+t] + lds[81+t]);
}

// ---------------- final: chain 3 solves from pose10, write output pose ----------------
__global__ __launch_bounds__(64) void k_solve(const float* __restrict__ S,
                                              const float* __restrict__ pose10,
                                              float* __restrict__ outp){
  __shared__ float sp[12];
  int t = threadIdx.x;
  wave_chain_solve(S, 3, pose10, sp, t);
  if (t == 0){
    #pragma unroll
    for (int k = 0; k < 12; k++) outp[k] = sp[k];
    outp[12] = 0.f; outp[13] = 0.f; outp[14] = 0.f; outp[15] = 1.f;
  }
}

extern "C" void kernel_launch(void* const* d_in, const int* in_sizes, int n_in,
                              void* d_out, int out_size, void* d_ws, size_t ws_size,
                              hipStream_t stream) {
  const float* pose10 = (const float*)d_in[0];
  const float* depth0 = (const float*)d_in[1];
  const float* depth1 = (const float*)d_in[2];
  const float* x0     = (const float*)d_in[3];
  const float* x1     = (const float*)d_in[4];
  const float* Kd     = (const float*)d_in[5];
  char* ws = (char*)d_ws;
  float* S    = (float*)(ws + WS_S_OFF);
  float* nx1  = (float*)(ws + WS_NX_OFF);
  float* outp = (float*)d_out;

  hipLaunchKernelGGL(k_pre, dim3(NBLK_ROW), dim3(256), 0, stream,
                     depth1, x1, Kd, S, nx1);
  for (int it = 0; it < 3; it++){
    hipLaunchKernelGGL(k_main, dim3(NBLK_MAIN), dim3(256), 0, stream,
                       depth0, x0, nx1, Kd, pose10, S, it);
  }
  hipLaunchKernelGGL(k_solve, dim3(1), dim3(64), 0, stream, S, pose10, outp);
}

// Round 10
// 213.645 us; speedup vs baseline: 1.0413x; 1.0413x over previous
//
#include <hip/hip_runtime.h>
#include <math.h>

#define HH 960
#define WW 1280
#define NPIX (HH*WW)
#define BPR (WW/256)              // 5 col-segments per image row
#define NBLK_ROW (NPIX/256)       // 4800 row-mapped tiles (pre phase)
#define NBLK_MAIN (NPIX/(256*4))  // 1200: 4-row x 256-col tiles (main phase, R11 proven)
#define PSTRIDE 28                // partial row stride (floats), 16B aligned

// workspace layout (bytes)
#define WS_POSE_OFF    0          // 16 floats
#define WS_PARTIAL_OFF 128        // 1200*28 floats = 134400 B
#define WS_NX_OFF      134528     // NPIX * 16 B = 19660800 B
#define WS_REC_OFF     19795328   // NPIX * 16 B = 19660800 B -> total ~39.5 MB

__device__ __forceinline__ int clampi(int v, int lo, int hi){ return v<lo?lo:(v>hi?hi:v); }

// pack two f32 -> one dword of 2 x f16 (lo = a, hi = b)
__device__ __forceinline__ float pack2h(float a, float b){
  _Float16 ha = (_Float16)a, hb = (_Float16)b;
  unsigned int u = ((unsigned int)__builtin_bit_cast(unsigned short, hb) << 16)
                 |  (unsigned int)__builtin_bit_cast(unsigned short, ha);
  return __builtin_bit_cast(float, u);
}
// unpack one dword of 2 x f16 -> (lo, hi) as f32
__device__ __forceinline__ float2 unpack2h(float p){
  unsigned int u = __builtin_bit_cast(unsigned int, p);
  _Float16 ha = __builtin_bit_cast(_Float16, (unsigned short)(u & 0xffffu));
  _Float16 hb = __builtin_bit_cast(_Float16, (unsigned short)(u >> 16));
  return make_float2((float)ha, (float)hb);
}

// ---------------- pre: pose copy + normals pack (image1) + gradient record (image0) ----------------
// R10 (kept): global depth-min/max invalidation dropped — verified bit-exact.
// R14 (kept): nx1 packed 16 B/pixel [d f32 | n f16x3 | rgb f16x3].
// R16: hoist the pose-INDEPENDENT RGB precompute out of k_main — sobel(x0) is recomputed
// 3x per pixel there. rec0[idx] = {gx|gy per ch (6 f16), C1=dot(gx,x0), C2=dot(gy,x0)}.
__global__ __launch_bounds__(256) void k_pre(const float* __restrict__ depth1,
                                             const float* __restrict__ x0,
                                             const float* __restrict__ x1,
                                             const float* __restrict__ Kd,
                                             const float* __restrict__ pose_in,
                                             float* __restrict__ pose,
                                             float* __restrict__ nx1,
                                             float* __restrict__ rec0){
  int t = threadIdx.x;
  if (blockIdx.x == 0 && t < 16) pose[t] = pose_in[t];
  int bid = blockIdx.x;
  int py = bid / BPR;
  int px = (bid % BPR)*256 + t;
  int idx = py*WW + px;
  float fx = Kd[0], fy = Kd[4], cx = Kd[2], cy = Kd[5];
  float invfx = 1.f/fx, invfy = 1.f/fy;

  // ---- image1: vertex-map sobel -> normal, pack with depth + color ----
  {
    float vx[3][3], vy[3][3], vz[3][3];
    #pragma unroll
    for (int dr = 0; dr < 3; dr++){
      int r = clampi(py + dr - 1, 0, HH-1);
      #pragma unroll
      for (int dc = 0; dc < 3; dc++){
        int c = clampi(px + dc - 1, 0, WW-1);
        float d = depth1[r*WW + c];
        vx[dr][dc] = ((float)c - cx)*invfx*d;
        vy[dr][dc] = ((float)r - cy)*invfy*d;
        vz[dr][dc] = d;
      }
    }
    float ax_ = (vx[0][2]-vx[0][0]) + 2.f*(vx[1][2]-vx[1][0]) + (vx[2][2]-vx[2][0]);
    float ay_ = (vy[0][2]-vy[0][0]) + 2.f*(vy[1][2]-vy[1][0]) + (vy[2][2]-vy[2][0]);
    float az_ = (vz[0][2]-vz[0][0]) + 2.f*(vz[1][2]-vz[1][0]) + (vz[2][2]-vz[2][0]);
    float bx_ = (vx[2][0]-vx[0][0]) + 2.f*(vx[2][1]-vx[0][1]) + (vx[2][2]-vx[0][2]);
    float by_ = (vy[2][0]-vy[0][0]) + 2.f*(vy[2][1]-vy[0][1]) + (vy[2][2]-vy[0][2]);
    float bz_ = (vz[2][0]-vz[0][0]) + 2.f*(vz[2][1]-vz[0][1]) + (vz[2][2]-vz[0][2]);
    float nx = ay_*bz_ - az_*by_;
    float ny = az_*bx_ - ax_*bz_;
    float nz = ax_*by_ - ay_*bx_;
    float nrm = sqrtf(nx*nx + ny*ny + nz*nz) + 1e-8f;
    float rn  = __builtin_amdgcn_rcpf(nrm);
    nx *= rn; ny *= rn; nz *= rn;
    float dcen = vz[1][1];
    const float* q = &x1[idx*3];
    float4 a;
    a.x = dcen;
    a.y = pack2h(nx, ny);
    a.z = pack2h(nz, q[0]);
    a.w = pack2h(q[1], q[2]);
    ((float4*)nx1)[idx] = a;
  }

  // ---- image0: normalized sobel gradients + center-color dots (pose-independent) ----
  {
    int rm = clampi(py-1, 0, HH-1), rp = clampi(py+1, 0, HH-1);
    int cm = clampi(px-1, 0, WW-1), cp = clampi(px+1, 0, WW-1);
    const float* p00 = &x0[(rm*WW+cm)*3];
    const float* p01 = &x0[(rm*WW+px)*3];
    const float* p02 = &x0[(rm*WW+cp)*3];
    const float* p10 = &x0[(py*WW+cm)*3];
    const float* p11 = &x0[(py*WW+px)*3];
    const float* p12 = &x0[(py*WW+cp)*3];
    const float* p20 = &x0[(rp*WW+cm)*3];
    const float* p21 = &x0[(rp*WW+px)*3];
    const float* p22 = &x0[(rp*WW+cp)*3];
    float gx[3], gy[3];
    float C1 = 0.f, C2 = 0.f;
    #pragma unroll
    for (int ch = 0; ch < 3; ch++){
      float a00 = p00[ch], a01 = p01[ch], a02 = p02[ch];
      float a10 = p10[ch],                a12 = p12[ch];
      float a20 = p20[ch], a21 = p21[ch], a22 = p22[ch];
      float dx = (a02-a00) + 2.f*(a12-a10) + (a22-a20);
      float dy = (a20-a00) + 2.f*(a21-a01) + (a22-a02);
      float rinv = __builtin_amdgcn_rsqf(dx*dx + dy*dy + 1e-8f);
      gx[ch] = dx*rinv; gy[ch] = dy*rinv;
      float c = p11[ch];
      C1 += gx[ch]*c; C2 += gy[ch]*c;
    }
    float4 r;
    r.x = pack2h(gx[0], gy[0]);
    r.y = pack2h(gx[1], gy[1]);
    r.z = pack2h(gx[2], gy[2]);
    r.w = pack2h(C1, C2);
    ((float4*)rec0)[idx] = r;
  }
}

// ---------------- fused per-pixel ICP + RGB accumulation (no LDS tile, XCD swizzle) ----------
// R11 geometry (4-row/256-thr/1200 blocks) + R14 packed gathers.
// R16: sobel hoisted to k_pre — no x0 staging, no tile barrier; RGB part is 4 unpacks +
// Gram-of-g + two dots against the gathered colors. LDS shrinks to the 432 B reducer.
__global__ __launch_bounds__(256) void k_main(const float* __restrict__ depth0,
                                              const float* __restrict__ rec0,
                                              const float* __restrict__ nx1,
                                              const float* __restrict__ Kd,
                                              const float* __restrict__ pose,
                                              float* __restrict__ partial){
  int t = threadIdx.x;
  // XCD-aware swizzle: contiguous 150-tile (120-row) band per XCD (R6: FETCH 92->29 MB)
  int bid = (blockIdx.x & 7)*(NBLK_MAIN/8) + (blockIdx.x >> 3);
  int pr = bid / BPR;
  int cs = bid % BPR;
  int py0 = pr*4;
  int px = cs*256 + t;

  int idx0 = py0*WW + px;
  float d0v[4];
  #pragma unroll
  for (int kp = 0; kp < 4; kp++) d0v[kp] = depth0[idx0 + kp*WW];

  float fx = Kd[0], fy = Kd[4], cx = Kd[2], cy = Kd[5];
  float inv_fx = 1.f/fx, inv_fy = 1.f/fy;
  float R00=pose[0], R01=pose[1], R02=pose[2],  tx=pose[3];
  float R10=pose[4], R11=pose[5], R12=pose[6],  ty=pose[7];
  float R20=pose[8], R21=pose[9], R22=pose[10], tz=pose[11];

  float acc[27];
  #pragma unroll
  for (int k = 0; k < 27; k++) acc[k] = 0.f;

  const float4* nx4 = (const float4*)nx1;
  const float4* rc4 = (const float4*)rec0;

  #pragma unroll
  for (int kp = 0; kp < 4; kp++){
    int py = py0 + kp;

    float d0 = d0v[kp];
    float4 rv = rc4[idx0 + kp*WW];      // own-pixel gradient record (coalesced)
    bool m0 = d0 > 0.f;
    float v0x = ((float)px - cx)*inv_fx*d0;
    float v0y = ((float)py - cy)*inv_fy*d0;
    float v0z = d0;
    float X = R00*v0x + R01*v0y + R02*v0z + tx;
    float Y = R10*v0x + R11*v0y + R12*v0z + ty;
    float Z = R20*v0x + R21*v0y + R22*v0z + tz;
    // 1/Z via rcp + one Newton step (drives u,v indices)
    float invZ = __builtin_amdgcn_rcpf(Z);
    invZ = invZ*(2.0f - Z*invZ);
    float u = X*invZ*fx + cx;
    float v = Y*invZ*fy + cy;
    bool inview = (u > 0.f) && (u < (float)(WW-1)) && (v > 0.f) && (v < (float)(HH-1)) && (Z > 0.f);

    float uc = fminf(fmaxf(u, 0.f), (float)(WW-1));
    float vc = fminf(fmaxf(v, 0.f), (float)(HH-1));
    float u0f = floorf(uc), v0f = floorf(vc);
    float wu = uc - u0f, wv = vc - v0f;
    int u0i = clampi((int)u0f, 0, WW-1);
    int v0i = clampi((int)v0f, 0, HH-1);
    int u1i = min(u0i + 1, WW-1);
    int v1i = min(v0i + 1, HH-1);
    int i00 = v0i*WW + u0i, i01 = v0i*WW + u1i, i10 = v1i*WW + u0i, i11 = v1i*WW + u1i;
    float w00 = (1.f-wu)*(1.f-wv), w01 = wu*(1.f-wv), w10 = (1.f-wu)*wv, w11 = wu*wv;

    float4 p00 = nx4[i00], p01 = nx4[i01], p10 = nx4[i10], p11v = nx4[i11];

    // unpack: .x = d (f32), .y = nx|ny, .z = nz|r, .w = g|b
    float2 nab00 = unpack2h(p00.y), nzr00 = unpack2h(p00.z);
    float2 nab01 = unpack2h(p01.y), nzr01 = unpack2h(p01.z);
    float2 nab10 = unpack2h(p10.y), nzr10 = unpack2h(p10.z);
    float2 nab11 = unpack2h(p11v.y), nzr11 = unpack2h(p11v.z);

    // factored vertex interpolation (d exact f32)
    float t0 = w00*p00.x, t1 = w01*p01.x, t2 = w10*p10.x, t3 = w11*p11v.x;
    float u0c = ((float)u0i - cx)*inv_fx, u1c = ((float)u1i - cx)*inv_fx;
    float v0c = ((float)v0i - cy)*inv_fy, v1c = ((float)v1i - cy)*inv_fy;
    float s2 = (t0+t1)+(t2+t3);
    float s0 = u0c*(t0+t2) + u1c*(t1+t3);
    float s1 = v0c*(t0+t1) + v1c*(t2+t3);
    float nx = nab00.x*w00 + nab01.x*w01 + nab10.x*w10 + nab11.x*w11;
    float ny = nab00.y*w00 + nab01.y*w01 + nab10.y*w10 + nab11.y*w11;
    float nz = nzr00.x*w00 + nzr01.x*w01 + nzr10.x*w10 + nzr11.x*w11;

    float dfx = X - s0, dfy = Y - s1, dfz = Z - s2;
    bool valid = inview && m0 && (s2 > 0.f) && (dfx*dfx + dfy*dfy + dfz*dfz < 0.01f);
    float res = 0.f;
    float J[6] = {0.f,0.f,0.f,0.f,0.f,0.f};
    if (valid){
      res = nx*dfx + ny*dfy + nz*dfz;
      J[0] = Y*nz - Z*ny;
      J[1] = Z*nx - X*nz;
      J[2] = X*ny - Y*nx;
      J[3] = nx; J[4] = ny; J[5] = nz;
    }
    float axv = fabsf(res);
    float rho = (axv <= 0.02f) ? axv*axv : (0.04f*axv - 0.0004f);
    float xs  = (axv < 1e-8f) ? 1.f : axv;
    float hw  = sqrtf(rho + 1e-16f) * __builtin_amdgcn_rcpf(xs);
    float wr  = hw*res;
    float wJ[6];
    #pragma unroll
    for (int i = 0; i < 6; i++) wJ[i] = hw*J[i];
    {
      int k = 0;
      #pragma unroll
      for (int i = 0; i < 6; i++)
        #pragma unroll
        for (int j = i; j < 6; j++)
          acc[k++] += wJ[i]*wJ[j];
      #pragma unroll
      for (int i = 0; i < 6; i++) acc[21+i] += wJ[i]*wr;
    }

    if (inview && m0){
      float2 gb00 = unpack2h(p00.w), gb01 = unpack2h(p01.w);
      float2 gb10 = unpack2h(p10.w), gb11 = unpack2h(p11v.w);
      float xw0 = nzr00.y*w00 + nzr01.y*w01 + nzr10.y*w10 + nzr11.y*w11;
      float xw1 = gb00.x*w00 + gb01.x*w01 + gb10.x*w10 + gb11.x*w11;
      float xw2 = gb00.y*w00 + gb01.y*w01 + gb10.y*w10 + gb11.y*w11;

      // hoisted gradients: g_ch = (gx,gy), C1 = dot(gx, x0), C2 = dot(gy, x0)
      float2 g0 = unpack2h(rv.x), g1 = unpack2h(rv.y), g2 = unpack2h(rv.z), cc = unpack2h(rv.w);
      float ga  = g0.x*g0.x + g1.x*g1.x + g2.x*g2.x;
      float gbv = g0.x*g0.y + g1.x*g1.y + g2.x*g2.y;
      float gc2 = g0.y*g0.y + g1.y*g1.y + g2.y*g2.y;
      float rx  = g0.x*xw0 + g1.x*xw1 + g2.x*xw2 - cc.x;
      float ry  = g0.y*xw0 + g1.y*xw1 + g2.y*xw2 - cc.y;
      ga *= 1e-6f; gbv *= 1e-6f; gc2 *= 1e-6f; rx *= 1e-6f; ry *= 1e-6f;

      float invD = __builtin_amdgcn_rcpf(d0), invD2 = invD*invD;
      float xy = v0x*v0y;
      float Jx[6] = { fx*(-invD2*xy), fx*(1.f + v0x*v0x*invD2), fx*(-v0y*invD), fx*invD, 0.f, fx*(-invD2*v0x) };
      float Jy[6] = { fy*(-1.f - invD2*v0y*v0y), fy*(xy*invD2), fy*(v0x*invD), 0.f, fy*invD, fy*(-invD2*v0y) };
      float P[6], Q[6];
      #pragma unroll
      for (int i = 0; i < 6; i++){ P[i] = ga*Jx[i] + gbv*Jy[i]; Q[i] = gbv*Jx[i] + gc2*Jy[i]; }
      int k = 0;
      #pragma unroll
      for (int i = 0; i < 6; i++)
        #pragma unroll
        for (int j = i; j < 6; j++)
          acc[k++] += Jx[j]*P[i] + Jy[j]*Q[i];
      #pragma unroll
      for (int i = 0; i < 6; i++) acc[21+i] += Jx[i]*rx + Jy[i]*ry;
    }
  }

  // block reduction: wave shfl -> LDS -> 27 floats per block (stride-28 rows)
  __shared__ float lds[108];
  int lane = t & 63;
  int wid  = t >> 6;
  #pragma unroll
  for (int k = 0; k < 27; k++){
    float vv = acc[k];
    vv += __shfl_down(vv, 32); vv += __shfl_down(vv, 16); vv += __shfl_down(vv, 8);
    vv += __shfl_down(vv, 4);  vv += __shfl_down(vv, 2);  vv += __shfl_down(vv, 1);
    if (lane == 0) lds[wid*27 + k] = vv;
  }
  __syncthreads();
  if (t < 27)
    partial[bid*PSTRIDE + t] = lds[t] + lds[27+t] + lds[54+t] + lds[81+t];
  else if (t == 27)
    partial[bid*PSTRIDE + 27] = 0.f;
}

// ---------------- final reduce + damped 6x6 solve + pose update (double) ----------------
__global__ __launch_bounds__(256) void k_solve(const float* __restrict__ partial,
                                               float* __restrict__ pose,
                                               float* __restrict__ outp){
  int t = threadIdx.x;
  double acc[PSTRIDE];
  #pragma unroll
  for (int k = 0; k < PSTRIDE; k++) acc[k] = 0.0;
  const float4* p4 = (const float4*)partial;
  for (int r = t; r < NBLK_MAIN; r += 256){
    #pragma unroll
    for (int q = 0; q < 7; q++){
      float4 vv = p4[r*7 + q];
      acc[q*4+0] += (double)vv.x;
      acc[q*4+1] += (double)vv.y;
      acc[q*4+2] += (double)vv.z;
      acc[q*4+3] += (double)vv.w;
    }
  }
  __shared__ double lds[4*PSTRIDE];
  int lane = t & 63, wid = t >> 6;
  #pragma unroll
  for (int k = 0; k < PSTRIDE; k++){
    double vv = acc[k];
    vv += __shfl_down(vv, 32); vv += __shfl_down(vv, 16); vv += __shfl_down(vv, 8);
    vv += __shfl_down(vv, 4);  vv += __shfl_down(vv, 2);  vv += __shfl_down(vv, 1);
    if (lane == 0) lds[wid*PSTRIDE + k] = vv;
  }
  __syncthreads();
  if (t == 0){
    double s[PSTRIDE];
    #pragma unroll
    for (int k = 0; k < PSTRIDE; k++)
      s[k] = lds[k] + lds[PSTRIDE+k] + lds[2*PSTRIDE+k] + lds[3*PSTRIDE+k];
    double Hm[6][6], b[6];
    {
      int k = 0;
      for (int i = 0; i < 6; i++)
        for (int j = i; j < 6; j++){ Hm[i][j] = s[k]; Hm[j][i] = s[k]; k++; }
      for (int i = 0; i < 6; i++) b[i] = s[21+i];
    }
    double tr = Hm[0][0]+Hm[1][1]+Hm[2][2]+Hm[3][3]+Hm[4][4]+Hm[5][5];
    for (int i = 0; i < 6; i++) Hm[i][i] += tr*0.001;
    double A[6][7];
    for (int i = 0; i < 6; i++){
      for (int j = 0; j < 6; j++) A[i][j] = Hm[i][j];
      A[i][6] = b[i];
    }
    for (int c = 0; c < 6; c++){
      int piv = c; double best = fabs(A[c][c]);
      for (int r = c+1; r < 6; r++){ double a = fabs(A[r][c]); if (a > best){ best = a; piv = r; } }
      if (piv != c)
        for (int j = 0; j < 7; j++){ double tv = A[c][j]; A[c][j] = A[piv][j]; A[piv][j] = tv; }
      double inv = 1.0/A[c][c];
      for (int r = 0; r < 6; r++){
        if (r == c) continue;
        double f = A[r][c]*inv;
        for (int j = c; j < 7; j++) A[r][j] -= f*A[c][j];
      }
    }
    double xi[6];
    for (int i = 0; i < 6; i++) xi[i] = A[i][6]/A[i][i];
    double wx = -xi[0], wy = -xi[1], wz = -xi[2];
    double th2 = wx*wx + wy*wy + wz*wz;
    if (th2 < 1e-30) th2 = 1e-30;
    double th = sqrt(th2);
    double dR[3][3];
    if (th <= 1e-10){
      dR[0][0]=1; dR[0][1]=0; dR[0][2]=0;
      dR[1][0]=0; dR[1][1]=1; dR[1][2]=0;
      dR[2][0]=0; dR[2][1]=0; dR[2][2]=1;
    } else {
      double sa = sin(th)/th;
      double sb = (1.0 - cos(th))/th2;
      double Wm[3][3] = {{0,-wz,wy},{wz,0,-wx},{-wy,wx,0}};
      double W2[3][3];
      for (int i = 0; i < 3; i++)
        for (int j = 0; j < 3; j++)
          W2[i][j] = Wm[i][0]*Wm[0][j] + Wm[i][1]*Wm[1][j] + Wm[i][2]*Wm[2][j];
      for (int i = 0; i < 3; i++)
        for (int j = 0; j < 3; j++)
          dR[i][j] = (i==j ? 1.0 : 0.0) + sa*Wm[i][j] + sb*W2[i][j];
    }
    double dt[3];
    for (int i = 0; i < 3; i++)
      dt[i] = -(dR[i][0]*xi[3] + dR[i][1]*xi[4] + dR[i][2]*xi[5]);
    double Ro[3][3], to[3];
    for (int i = 0; i < 3; i++){
      for (int j = 0; j < 3; j++) Ro[i][j] = (double)pose[i*4+j];
      to[i] = (double)pose[i*4+3];
    }
    double Rn[3][3], tn[3];
    for (int i = 0; i < 3; i++){
      for (int j = 0; j < 3; j++)
        Rn[i][j] = dR[i][0]*Ro[0][j] + dR[i][1]*Ro[1][j] + dR[i][2]*Ro[2][j];
      tn[i] = dR[i][0]*to[0] + dR[i][1]*to[1] + dR[i][2]*to[2] + dt[i];
    }
    float o16[16];
    for (int i = 0; i < 3; i++){
      for (int j = 0; j < 3; j++) o16[i*4+j] = (float)Rn[i][j];
      o16[i*4+3] = (float)tn[i];
    }
    o16[12] = 0.f; o16[13] = 0.f; o16[14] = 0.f; o16[15] = 1.f;
    for (int k = 0; k < 16; k++){ pose[k] = o16[k]; outp[k] = o16[k]; }
  }
}

extern "C" void kernel_launch(void* const* d_in, const int* in_sizes, int n_in,
                              void* d_out, int out_size, void* d_ws, size_t ws_size,
                              hipStream_t stream) {
  const float* pose10 = (const float*)d_in[0];
  const float* depth0 = (const float*)d_in[1];
  const float* depth1 = (const float*)d_in[2];
  const float* x0     = (const float*)d_in[3];
  const float* x1     = (const float*)d_in[4];
  const float* Kd     = (const float*)d_in[5];
  char* ws = (char*)d_ws;
  float* pose    = (float*)(ws + WS_POSE_OFF);
  float* partial = (float*)(ws + WS_PARTIAL_OFF);
  float* nx1     = (float*)(ws + WS_NX_OFF);
  float* rec0    = (float*)(ws + WS_REC_OFF);
  float* outp    = (float*)d_out;

  hipLaunchKernelGGL(k_pre, dim3(NBLK_ROW), dim3(256), 0, stream,
                     depth1, x0, x1, Kd, pose10, pose, nx1, rec0);
  for (int it = 0; it < 3; it++){
    hipLaunchKernelGGL(k_main,  dim3(NBLK_MAIN), dim3(256), 0, stream,
                       depth0, rec0, nx1, Kd, pose, partial);
    hipLaunchKernelGGL(k_solve, dim3(1),         dim3(256), 0, stream, partial, pose, outp);
  }
}